// Round 4
// baseline (353.699 us; speedup 1.0000x reference)
//
#include <hip/hip_runtime.h>

#define NN 50000
#define NE 400000
#define INF 768
#define HF 16
#define OF 21
#define ELLW 40   // Poisson(8) max-degree guard: P(deg>=40 anywhere) ~ 1e-11

#define FMA4(ACC, SS, VV) { (ACC).x += (SS)*(VV).x; (ACC).y += (SS)*(VV).y; \
                            (ACC).z += (SS)*(VV).z; (ACC).w += (SS)*(VV).w; }

// -----------------------------------------------------------------------------
// ELL build: cnt[d] = in-degree, ell[d*ELLW+i] = src of i-th edge into d.
// -----------------------------------------------------------------------------
__global__ __launch_bounds__(256) void scatter_kernel(const int* __restrict__ src,
                                                      const int* __restrict__ dst,
                                                      int* __restrict__ cnt,
                                                      int* __restrict__ ell) {
    int e = blockIdx.x * 256 + threadIdx.x;
    if (e >= NE) return;
    int d = dst[e];
    int pos = atomicAdd(&cnt[d], 1);
    if (pos < ELLW) ell[d * ELLW + pos] = src[e];
}

// -----------------------------------------------------------------------------
// GEMM1: P = F @ W1  (50000x768 @ 768x16).
// Round-8 theory: R3's loop stalled because vmcnt is FIFO — the fc=fn register
// copies forced vmcnt(0) every tile, draining the F prefetch queue; each of 12
// tiles paid ~900cy HBM latency with 2 waves/SIMD. Fix:
//  (a) W1 in LDS -> W waits use lgkmcnt, which CANNOT drain F global loads.
//      Permuted layout [m][k>>2][jq]: granule(k,jq) = (k&3)*768 + (k>>6)*64
//      + ((k>>4)&3)*16 + ((k>>2)&3)*4 + jq. A tile-T/m read is then
//      addr = lane*16 + T*1024 + m*12288 — 64 CONSECUTIVE granules,
//      conflict-free ds_read_b128, 4 reads/tile/wave.
//  (b) true 4-deep F pipeline: q[T&3] computes tile T then refills tile T+4;
//      steady-state wait is vmcnt(12) (3 batches always in flight), no copies,
//      no drains.
//  (c) block=512 shares the 48KB stage; __launch_bounds__(512,4) caps VGPR at
//      128 vs ~115 live (acc16+q64+w16) -> no spill, 16 waves/CU.
// -----------------------------------------------------------------------------
__global__ __launch_bounds__(512, 4) void gemm1_kernel(const float* __restrict__ F,
                                                       const float* __restrict__ W1,
                                                       float* __restrict__ P) {
    __shared__ float Ws[INF * HF];   // 48 KB, permuted

    const int tid = threadIdx.x;
    for (int i = tid; i < (INF * HF) / 4; i += 512) {
        const int k = i >> 2, jq = i & 3;
        const int dg = (k & 3) * 768 + (k >> 6) * 64 + (((k >> 4) & 3) << 4)
                     + (((k >> 2) & 3) << 2) + jq;
        *(float4*)(Ws + dg * 4) = *(const float4*)(W1 + i * 4);
    }
    __syncthreads();

    const int wv = tid >> 6, lane = tid & 63;
    const int jq = lane & 3;          // j-quad this lane accumulates
    const int koff = lane & 60;       // lane's k offset within a 64-k tile
    const int rowbase = blockIdx.x * 32 + wv * 4;

    int roff[4];
#pragma unroll
    for (int r = 0; r < 4; ++r) {
        int row = rowbase + r;
        if (row > NN - 1) row = NN - 1;      // tail clamp: safe read, write masked
        roff[r] = row * INF + koff;
    }

    const float* lw = Ws + lane * 4;  // + j*256 + m*3072 (+g4*1024) as immediates

    float4 acc[4];
#pragma unroll
    for (int r = 0; r < 4; ++r) acc[r] = make_float4(0.f, 0.f, 0.f, 0.f);

    float4 q[4][4];                   // [tile-slot][row] — all indices static
#pragma unroll
    for (int j = 0; j < 4; ++j)
#pragma unroll
        for (int r = 0; r < 4; ++r)
            q[j][r] = *(const float4*)(F + roff[r] + j * 64);

#pragma unroll 1
    for (int g4 = 0; g4 < 2; ++g4) {          // tile groups {0..3},{4..7}
        const float* lwg = lw + g4 * 1024;
        const int foff = g4 * 256 + 256;      // F col offset of tile T+4
#pragma unroll
        for (int j = 0; j < 4; ++j) {
            const float4 w0 = *(const float4*)(lwg + j * 256 + 0 * 3072);
            const float4 w1 = *(const float4*)(lwg + j * 256 + 1 * 3072);
            const float4 w2 = *(const float4*)(lwg + j * 256 + 2 * 3072);
            const float4 w3 = *(const float4*)(lwg + j * 256 + 3 * 3072);
#pragma unroll
            for (int r = 0; r < 4; ++r) {
                FMA4(acc[r], q[j][r].x, w0);
                FMA4(acc[r], q[j][r].y, w1);
                FMA4(acc[r], q[j][r].z, w2);
                FMA4(acc[r], q[j][r].w, w3);
            }
#pragma unroll
            for (int r = 0; r < 4; ++r)       // refill slot j with tile T+4
                q[j][r] = *(const float4*)(F + roff[r] + foff + j * 64);
        }
    }
    {   // epilogue group: tiles 8..11, no further prefetch
        const float* lwg = lw + 2048;
#pragma unroll
        for (int j = 0; j < 4; ++j) {
            const float4 w0 = *(const float4*)(lwg + j * 256 + 0 * 3072);
            const float4 w1 = *(const float4*)(lwg + j * 256 + 1 * 3072);
            const float4 w2 = *(const float4*)(lwg + j * 256 + 2 * 3072);
            const float4 w3 = *(const float4*)(lwg + j * 256 + 3 * 3072);
#pragma unroll
            for (int r = 0; r < 4; ++r) {
                FMA4(acc[r], q[j][r].x, w0);
                FMA4(acc[r], q[j][r].y, w1);
                FMA4(acc[r], q[j][r].z, w2);
                FMA4(acc[r], q[j][r].w, w3);
            }
        }
    }

#pragma unroll
    for (int r = 0; r < 4; ++r) {
        float4 v = acc[r];
#define RED(X) { v.X += __shfl_xor(v.X, 4);  v.X += __shfl_xor(v.X, 8); \
                 v.X += __shfl_xor(v.X, 16); v.X += __shfl_xor(v.X, 32); }
        RED(x) RED(y) RED(z) RED(w)
#undef RED
        const int row = rowbase + r;
        if (lane < 4 && row < NN)
            *(float4*)(P + (size_t)row * HF + jq * 4) = v;
    }
}

// -----------------------------------------------------------------------------
// agg1: A1[n] = sum_{e into n} P[src[e]]. 16 lanes per node: 4 edge-subgroups
// (es) x 4 float4-lanes (q). Butterfly xor 4,8 merges edge groups.
// -----------------------------------------------------------------------------
__global__ __launch_bounds__(256) void agg1_kernel(const float* __restrict__ P,
                                                   const int* __restrict__ cnt,
                                                   const int* __restrict__ ell,
                                                   float* __restrict__ A1) {
    int g = blockIdx.x * 256 + threadIdx.x;
    int node = g >> 4;
    if (node >= NN) return;
    const int l = g & 15, es = l >> 2, q = l & 3;
    int c = cnt[node]; if (c > ELLW) c = ELLW;
    const int* ep = ell + node * ELLW;

    float4 v = {0,0,0,0};
    for (int i = es; i < c; i += 4) {
        int s = ep[i];
        float4 p = *(const float4*)(P + (size_t)s * HF + q * 4);
        v.x += p.x; v.y += p.y; v.z += p.z; v.w += p.w;
    }
#define BFLY2(VAL) { VAL += __shfl_xor(VAL, 4); VAL += __shfl_xor(VAL, 8); }
    BFLY2(v.x) BFLY2(v.y) BFLY2(v.z) BFLY2(v.w)
#undef BFLY2
    if (es == 0)
        *(float4*)(A1 + (size_t)node * HF + q * 4) = v;
}

// -----------------------------------------------------------------------------
// agg2 + output GEMM fused: A2[n] = sum relu(A1[src]+b1) (16 lanes/node),
// then out[n] = A2 @ W2 + b2 via per-q partials + xor 1,2 butterfly.
// -----------------------------------------------------------------------------
__global__ __launch_bounds__(256) void agg2out_kernel(const float* __restrict__ A1,
                                                      const float* __restrict__ b1,
                                                      const int* __restrict__ cnt,
                                                      const int* __restrict__ ell,
                                                      const float* __restrict__ W2,
                                                      const float* __restrict__ b2,
                                                      float* __restrict__ out) {
    __shared__ float W2s[HF * OF];
    __shared__ float b2s[OF];
    const int t = threadIdx.x;
    for (int i = t; i < HF * OF; i += 256) W2s[i] = W2[i];
    if (t < OF) b2s[t] = b2[t];
    __syncthreads();

    int g = blockIdx.x * 256 + t;
    int node = g >> 4;
    if (node >= NN) return;
    const int l = g & 15, es = l >> 2, q = l & 3;

    const float4 bb = *(const float4*)(b1 + q * 4);
    int c = cnt[node]; if (c > ELLW) c = ELLW;
    const int* ep = ell + node * ELLW;

    float4 v = {0,0,0,0};
    for (int i = es; i < c; i += 4) {
        int s = ep[i];
        float4 h = *(const float4*)(A1 + (size_t)s * HF + q * 4);
        h.x = fmaxf(h.x + bb.x, 0.0f);
        h.y = fmaxf(h.y + bb.y, 0.0f);
        h.z = fmaxf(h.z + bb.z, 0.0f);
        h.w = fmaxf(h.w + bb.w, 0.0f);
        v.x += h.x; v.y += h.y; v.z += h.z; v.w += h.w;
    }
#define BFLY2(VAL) { VAL += __shfl_xor(VAL, 4); VAL += __shfl_xor(VAL, 8); }
    BFLY2(v.x) BFLY2(v.y) BFLY2(v.z) BFLY2(v.w)
#undef BFLY2

    const float* w0 = W2s + (q * 4 + 0) * OF;
    const float* w1 = W2s + (q * 4 + 1) * OF;
    const float* w2 = W2s + (q * 4 + 2) * OF;
    const float* w3 = W2s + (q * 4 + 3) * OF;
    float o[OF];
#pragma unroll
    for (int cc = 0; cc < OF; ++cc)
        o[cc] = v.x * w0[cc] + v.y * w1[cc] + v.z * w2[cc] + v.w * w3[cc];
#pragma unroll
    for (int cc = 0; cc < OF; ++cc) {
        o[cc] += __shfl_xor(o[cc], 1);
        o[cc] += __shfl_xor(o[cc], 2);
    }
    if (es == 0) {
        float* op = out + (size_t)node * OF;
        for (int cc = q; cc < OF; cc += 4) op[cc] = o[cc] + b2s[cc];
    }
}

extern "C" void kernel_launch(void* const* d_in, const int* in_sizes, int n_in,
                              void* d_out, int out_size, void* d_ws, size_t ws_size,
                              hipStream_t stream) {
    const float* F   = (const float*)d_in[0];
    const float* W1  = (const float*)d_in[1];
    const float* b1  = (const float*)d_in[2];
    const float* W2  = (const float*)d_in[3];
    const float* b2  = (const float*)d_in[4];
    const int*   src = (const int*)d_in[5];
    const int*   dst = (const int*)d_in[6];
    float* out = (float*)d_out;

    char* ws = (char*)d_ws;
    int*   cnt = (int*)(ws);                       // 200,000 B
    int*   ell = (int*)(ws + 200192);              // 8,000,000 B
    float* P   = (float*)(ws + 8200192);           // 3,200,000 B
    float* A1  = (float*)(ws + 11400192);          // 3,200,000 B

    (void)hipMemsetAsync(cnt, 0, NN * sizeof(int), stream);
    scatter_kernel<<<(NE + 255) / 256, 256, 0, stream>>>(src, dst, cnt, ell);
    gemm1_kernel<<<(NN + 31) / 32, 512, 0, stream>>>(F, W1, P);
    agg1_kernel<<<(NN * 16 + 255) / 256, 256, 0, stream>>>(P, cnt, ell, A1);
    agg2out_kernel<<<(NN * 16 + 255) / 256, 256, 0, stream>>>(A1, b1, cnt, ell, W2, b2, out);
}

// Round 5
// 300.588 us; speedup vs baseline: 1.1767x; 1.1767x over previous
//
#include <hip/hip_runtime.h>

#define NN 50000
#define NE 400000
#define INF 768
#define HF 16
#define OF 21
#define ELLW 40   // Poisson(8) max-degree guard: P(deg>=40 anywhere) ~ 1e-11

#define FMA4(ACC, SS, VV) { (ACC).x += (SS)*(VV).x; (ACC).y += (SS)*(VV).y; \
                            (ACC).z += (SS)*(VV).z; (ACC).w += (SS)*(VV).w; }

// -----------------------------------------------------------------------------
// ELL build: cnt[d] = in-degree, ell[d*ELLW+i] = src of i-th edge into d.
// -----------------------------------------------------------------------------
__global__ __launch_bounds__(256) void scatter_kernel(const int* __restrict__ src,
                                                      const int* __restrict__ dst,
                                                      int* __restrict__ cnt,
                                                      int* __restrict__ ell) {
    int e = blockIdx.x * 256 + threadIdx.x;
    if (e >= NE) return;
    int d = dst[e];
    int pos = atomicAdd(&cnt[d], 1);
    if (pos < ELLW) ell[d * ELLW + pos] = src[e];
}

// direct global->LDS async copy, 16B per lane. LDS dst must be wave-uniform
// (HW writes at dst + lane*16); global src is per-lane.
__device__ __forceinline__ void gload_lds16(const float* g, float* l) {
    __builtin_amdgcn_global_load_lds(
        (const __attribute__((address_space(1))) unsigned int*)g,
        (__attribute__((address_space(3))) unsigned int*)l,
        16, 0, 0);
}

// -----------------------------------------------------------------------------
// GEMM1: P = F @ W1  (50000x768 @ 768x16).
// Round-9 state of knowledge:
//  - R1/R4: any multi-tile F pipeline held in VGPRs gets spilled (allocator
//    picks a low notch — 40/64 regs — and dumps the array: WRITE_SIZE 134MB).
//  - R0/R2 (no spill) sit at ~85-94us: latency-bound. Required in-flight bytes
//    per CU = 23GB/s x 375ns ~ 8.8KB; register schemes carry ~0.5KB.
// Fix: pipeline depth in LDS via global_load_lds (m97 structure). Per block
// (512 thr, 64 rows): W1 48KB permuted + F double-buffer 2x16KB = 80KB LDS
// -> 2 blocks/CU. Per tile each wave issues 2 global_load_lds (1KB each) for
// tile t+1, computes tile t from LDS, __syncthreads. One 16KB tile in flight
// per block = 2x the latency-hiding requirement -> BW-bound.
// W permuted layout: granule dg(k,jq) = (k&3)*768 + (k>>6)*64 + ((k>>4)&3)*16
// + ((k>>2)&3)*4 + jq, so lane's 4 W-frag reads for tile t are at byte
// lane*16 + t*1024 + m*12288 — contiguous wave-wide, conflict-free reads.
// F tile layout [64 rows][64 k]: ds_read_b128 at row*256 + (g*16+ks*4)*4 is
// 16 granules x 4-way broadcast, worst 2-way bank alias (free).
// Per-thread state: acc[8]=32 + Wfrag 16 + temps ~ 65 regs, all static
// indices; launch_bounds(512,2) leaves cap 256 (LDS caps occupancy anyway).
// -----------------------------------------------------------------------------
__global__ __launch_bounds__(512, 2) void gemm1_kernel(const float* __restrict__ F,
                                                       const float* __restrict__ W1,
                                                       float* __restrict__ P) {
    __shared__ float Ws[INF * HF];       // 48 KB, permuted
    __shared__ float Fb[2][64 * 64];     // 2 x 16 KB, [row][k] per tile

    const int tid = threadIdx.x;
    for (int i = tid; i < (INF * HF) / 4; i += 512) {
        const int k = i >> 2, jq = i & 3;
        const int dg = (k & 3) * 768 + (k >> 6) * 64 + (((k >> 4) & 3) << 4)
                     + (((k >> 2) & 3) << 2) + jq;
        *(float4*)(Ws + dg * 4) = *(const float4*)(W1 + i * 4);
    }

    const int wv = tid >> 6, lane = tid & 63;
    const int jq = lane & 3;             // j-quad this lane accumulates
    const int koff = lane & 60;          // lane's k offset within a 64-k tile
    const int rowbase = blockIdx.x * 64;

    // per-lane global staging pointers (2 instrs/wave: 4 rows each)
    const int colb = (lane & 15) * 4;
    int srow0 = rowbase + wv * 8 + 0 + (lane >> 4);
    int srow1 = rowbase + wv * 8 + 4 + (lane >> 4);
    if (srow0 > NN - 1) srow0 = NN - 1;  // tail clamp: safe read, write masked
    if (srow1 > NN - 1) srow1 = NN - 1;
    const float* sp0 = F + (size_t)srow0 * INF + colb;
    const float* sp1 = F + (size_t)srow1 * INF + colb;
    // wave-uniform LDS dsts for the 2 staging instrs
    float* ld0a = &Fb[0][wv * 512];        float* ld0b = &Fb[0][wv * 512 + 256];
    float* ld1a = &Fb[1][wv * 512];        float* ld1b = &Fb[1][wv * 512 + 256];

    // stage tile 0 into buffer 0
    gload_lds16(sp0, ld0a);
    gload_lds16(sp1, ld0b);

    const float* lw = Ws + lane * 4;     // + t*256 + m*3072 as immediates

    float4 acc[8];
#pragma unroll
    for (int r = 0; r < 8; ++r) acc[r] = make_float4(0.f, 0.f, 0.f, 0.f);

    __syncthreads();                     // W stage + tile0 complete

#pragma unroll 1
    for (int t = 0; t < 12; ++t) {
        if (t < 11) {                    // issue next tile into other buffer
            const int c = (t + 1) * 64;
            if ((t & 1) == 0) { gload_lds16(sp0 + c, ld1a); gload_lds16(sp1 + c, ld1b); }
            else              { gload_lds16(sp0 + c, ld0a); gload_lds16(sp1 + c, ld0b); }
        }
        const float* lwt = lw + t * 256;
        const float4 w0 = *(const float4*)(lwt + 0 * 3072);
        const float4 w1 = *(const float4*)(lwt + 1 * 3072);
        const float4 w2 = *(const float4*)(lwt + 2 * 3072);
        const float4 w3 = *(const float4*)(lwt + 3 * 3072);
        const float* fb = &Fb[t & 1][koff];
#pragma unroll
        for (int r = 0; r < 8; ++r) {
            const float4 f = *(const float4*)(fb + (wv * 8 + r) * 64);
            FMA4(acc[r], f.x, w0);
            FMA4(acc[r], f.y, w1);
            FMA4(acc[r], f.z, w2);
            FMA4(acc[r], f.w, w3);
        }
        __syncthreads();                 // next-tile stage complete, buf reusable
    }

#pragma unroll
    for (int r = 0; r < 8; ++r) {
        float4 v = acc[r];
#define RED(X) { v.X += __shfl_xor(v.X, 4);  v.X += __shfl_xor(v.X, 8); \
                 v.X += __shfl_xor(v.X, 16); v.X += __shfl_xor(v.X, 32); }
        RED(x) RED(y) RED(z) RED(w)
#undef RED
        const int row = rowbase + wv * 8 + r;
        if (lane < 4 && row < NN)
            *(float4*)(P + (size_t)row * HF + jq * 4) = v;
    }
}

// -----------------------------------------------------------------------------
// agg1: A1[n] = sum_{e into n} P[src[e]]. 16 lanes per node: 4 edge-subgroups
// (es) x 4 float4-lanes (q). Butterfly xor 4,8 merges edge groups.
// -----------------------------------------------------------------------------
__global__ __launch_bounds__(256) void agg1_kernel(const float* __restrict__ P,
                                                   const int* __restrict__ cnt,
                                                   const int* __restrict__ ell,
                                                   float* __restrict__ A1) {
    int g = blockIdx.x * 256 + threadIdx.x;
    int node = g >> 4;
    if (node >= NN) return;
    const int l = g & 15, es = l >> 2, q = l & 3;
    int c = cnt[node]; if (c > ELLW) c = ELLW;
    const int* ep = ell + node * ELLW;

    float4 v = {0,0,0,0};
    for (int i = es; i < c; i += 4) {
        int s = ep[i];
        float4 p = *(const float4*)(P + (size_t)s * HF + q * 4);
        v.x += p.x; v.y += p.y; v.z += p.z; v.w += p.w;
    }
#define BFLY2(VAL) { VAL += __shfl_xor(VAL, 4); VAL += __shfl_xor(VAL, 8); }
    BFLY2(v.x) BFLY2(v.y) BFLY2(v.z) BFLY2(v.w)
#undef BFLY2
    if (es == 0)
        *(float4*)(A1 + (size_t)node * HF + q * 4) = v;
}

// -----------------------------------------------------------------------------
// agg2 + output GEMM fused: A2[n] = sum relu(A1[src]+b1) (16 lanes/node),
// then out[n] = A2 @ W2 + b2 via per-q partials + xor 1,2 butterfly.
// -----------------------------------------------------------------------------
__global__ __launch_bounds__(256) void agg2out_kernel(const float* __restrict__ A1,
                                                      const float* __restrict__ b1,
                                                      const int* __restrict__ cnt,
                                                      const int* __restrict__ ell,
                                                      const float* __restrict__ W2,
                                                      const float* __restrict__ b2,
                                                      float* __restrict__ out) {
    __shared__ float W2s[HF * OF];
    __shared__ float b2s[OF];
    const int t = threadIdx.x;
    for (int i = t; i < HF * OF; i += 256) W2s[i] = W2[i];
    if (t < OF) b2s[t] = b2[t];
    __syncthreads();

    int g = blockIdx.x * 256 + t;
    int node = g >> 4;
    if (node >= NN) return;
    const int l = g & 15, es = l >> 2, q = l & 3;

    const float4 bb = *(const float4*)(b1 + q * 4);
    int c = cnt[node]; if (c > ELLW) c = ELLW;
    const int* ep = ell + node * ELLW;

    float4 v = {0,0,0,0};
    for (int i = es; i < c; i += 4) {
        int s = ep[i];
        float4 h = *(const float4*)(A1 + (size_t)s * HF + q * 4);
        h.x = fmaxf(h.x + bb.x, 0.0f);
        h.y = fmaxf(h.y + bb.y, 0.0f);
        h.z = fmaxf(h.z + bb.z, 0.0f);
        h.w = fmaxf(h.w + bb.w, 0.0f);
        v.x += h.x; v.y += h.y; v.z += h.z; v.w += h.w;
    }
#define BFLY2(VAL) { VAL += __shfl_xor(VAL, 4); VAL += __shfl_xor(VAL, 8); }
    BFLY2(v.x) BFLY2(v.y) BFLY2(v.z) BFLY2(v.w)
#undef BFLY2

    const float* w0 = W2s + (q * 4 + 0) * OF;
    const float* w1 = W2s + (q * 4 + 1) * OF;
    const float* w2 = W2s + (q * 4 + 2) * OF;
    const float* w3 = W2s + (q * 4 + 3) * OF;
    float o[OF];
#pragma unroll
    for (int cc = 0; cc < OF; ++cc)
        o[cc] = v.x * w0[cc] + v.y * w1[cc] + v.z * w2[cc] + v.w * w3[cc];
#pragma unroll
    for (int cc = 0; cc < OF; ++cc) {
        o[cc] += __shfl_xor(o[cc], 1);
        o[cc] += __shfl_xor(o[cc], 2);
    }
    if (es == 0) {
        float* op = out + (size_t)node * OF;
        for (int cc = q; cc < OF; cc += 4) op[cc] = o[cc] + b2s[cc];
    }
}

extern "C" void kernel_launch(void* const* d_in, const int* in_sizes, int n_in,
                              void* d_out, int out_size, void* d_ws, size_t ws_size,
                              hipStream_t stream) {
    const float* F   = (const float*)d_in[0];
    const float* W1  = (const float*)d_in[1];
    const float* b1  = (const float*)d_in[2];
    const float* W2  = (const float*)d_in[3];
    const float* b2  = (const float*)d_in[4];
    const int*   src = (const int*)d_in[5];
    const int*   dst = (const int*)d_in[6];
    float* out = (float*)d_out;

    char* ws = (char*)d_ws;
    int*   cnt = (int*)(ws);                       // 200,000 B
    int*   ell = (int*)(ws + 200192);              // 8,000,000 B
    float* P   = (float*)(ws + 8200192);           // 3,200,000 B
    float* A1  = (float*)(ws + 11400192);          // 3,200,000 B

    (void)hipMemsetAsync(cnt, 0, NN * sizeof(int), stream);
    scatter_kernel<<<(NE + 255) / 256, 256, 0, stream>>>(src, dst, cnt, ell);
    gemm1_kernel<<<(NN + 63) / 64, 512, 0, stream>>>(F, W1, P);
    agg1_kernel<<<(NN * 16 + 255) / 256, 256, 0, stream>>>(P, cnt, ell, A1);
    agg2out_kernel<<<(NN * 16 + 255) / 256, 256, 0, stream>>>(A1, b1, cnt, ell, W2, b2, out);
}